// Round 2
// baseline (324.899 us; speedup 1.0000x reference)
//
#include <hip/hip_runtime.h>

constexpr int DIMN = 160;                 // D = H = W
constexpr int VOL  = DIMN * DIMN * DIMN;  // 4,096,000
constexpr int BATCH = 2;
constexpr long long NPTS = (long long)BATCH * VOL;  // 8,192,000

// ---------------------------------------------------------------------------
// Kernel A: 5x5x5 conv, replicate padding 2, C_in = C_out = 1.
// Thread strip: 5 outputs along W via sliding register window.
// Block (32,8): 32 strips cover W=160, 8 rows of H. Grid (H/8, D, B).
// ---------------------------------------------------------------------------
__global__ __launch_bounds__(256) void conv3d_rep(
    const float* __restrict__ x, const float* __restrict__ w,
    float* __restrict__ y)
{
    __shared__ float ws[125];
    {
        int t = threadIdx.y * 32 + threadIdx.x;
        if (t < 125) ws[t] = w[t];
    }
    __syncthreads();

    const int tx = threadIdx.x;            // 0..31
    const int ty = threadIdx.y;            // 0..7
    const int yy0 = blockIdx.x * 8 + ty;   // H index
    const int z   = blockIdx.y;            // D index
    const int b   = blockIdx.z;            // batch
    const int x0  = tx * 5;                // W start of strip

    // clamped W indices for the 9-wide window [x0-2, x0+6]
    int xi[9];
#pragma unroll
    for (int j = 0; j < 9; ++j) {
        int xx = x0 - 2 + j;
        xi[j] = xx < 0 ? 0 : (xx > DIMN - 1 ? DIMN - 1 : xx);
    }

    const float* xb = x + (size_t)b * VOL;
    float acc[5] = {0.f, 0.f, 0.f, 0.f, 0.f};

#pragma unroll
    for (int kz = 0; kz < 5; ++kz) {
        int zz = z + kz - 2;
        zz = zz < 0 ? 0 : (zz > DIMN - 1 ? DIMN - 1 : zz);
#pragma unroll
        for (int ky = 0; ky < 5; ++ky) {
            int yy = yy0 + ky - 2;
            yy = yy < 0 ? 0 : (yy > DIMN - 1 ? DIMN - 1 : yy);
            const float* row = xb + ((size_t)zz * DIMN + yy) * DIMN;
            float v[9];
#pragma unroll
            for (int j = 0; j < 9; ++j) v[j] = row[xi[j]];
            const float* wr = ws + (kz * 5 + ky) * 5;
#pragma unroll
            for (int kx = 0; kx < 5; ++kx) {
                const float wv = wr[kx];
#pragma unroll
                for (int t = 0; t < 5; ++t) acc[t] = fmaf(wv, v[kx + t], acc[t]);
            }
        }
    }

    float* yrow = y + (((size_t)b * DIMN + z) * DIMN + yy0) * DIMN + x0;
#pragma unroll
    for (int t = 0; t < 5; ++t) yrow[t] = acc[t];
}

// ---------------------------------------------------------------------------
// Kernel B: Hessian (jnp.gradient twice) + MLP + sigmoid, per point.
// Branch-free gradient: g = s * (y[p+] - y[p-]), clamped offsets,
// s = 1 at edges (one-sided), 0.5 interior. Applied twice per component.
// ---------------------------------------------------------------------------
__device__ __forceinline__ float yld(const float* __restrict__ Y,
                                     int z, int y, int x)
{
    return Y[((size_t)z * DIMN + y) * DIMN + x];
}

__device__ __forceinline__ float GX(const float* __restrict__ Y,
                                    int z, int y, int x)
{
    const int a = x > 0 ? x - 1 : 0;
    const int c = x < DIMN - 1 ? x + 1 : DIMN - 1;
    const float s = (x > 0 && x < DIMN - 1) ? 0.5f : 1.0f;
    return s * (yld(Y, z, y, c) - yld(Y, z, y, a));
}
__device__ __forceinline__ float GY(const float* __restrict__ Y,
                                    int z, int y, int x)
{
    const int a = y > 0 ? y - 1 : 0;
    const int c = y < DIMN - 1 ? y + 1 : DIMN - 1;
    const float s = (y > 0 && y < DIMN - 1) ? 0.5f : 1.0f;
    return s * (yld(Y, z, c, x) - yld(Y, z, a, x));
}
__device__ __forceinline__ float GZ(const float* __restrict__ Y,
                                    int z, int y, int x)
{
    const int a = z > 0 ? z - 1 : 0;
    const int c = z < DIMN - 1 ? z + 1 : DIMN - 1;
    const float s = (z > 0 && z < DIMN - 1) ? 0.5f : 1.0f;
    return s * (yld(Y, c, y, x) - yld(Y, a, y, x));
}

__global__ __launch_bounds__(256) void hess_mlp(
    const float* __restrict__ Yg,
    const float* __restrict__ w1, const float* __restrict__ b1,
    const float* __restrict__ w2, const float* __restrict__ b2,
    float* __restrict__ out)
{
    const int idx = blockIdx.x * 256 + threadIdx.x;   // < 8,192,000
    const int b   = idx / VOL;
    int rem       = idx - b * VOL;
    const int z   = rem / (DIMN * DIMN);
    rem          -= z * (DIMN * DIMN);
    const int y   = rem / DIMN;
    const int x   = rem - y * DIMN;

    const float* Y = Yg + (size_t)b * VOL;

    const int zm = z > 0 ? z - 1 : 0, zp = z < DIMN - 1 ? z + 1 : DIMN - 1;
    const int ym = y > 0 ? y - 1 : 0, yp = y < DIMN - 1 ? y + 1 : DIMN - 1;
    const int xm = x > 0 ? x - 1 : 0, xp = x < DIMN - 1 ? x + 1 : DIMN - 1;
    const float sz = (z > 0 && z < DIMN - 1) ? 0.5f : 1.0f;
    const float sy = (y > 0 && y < DIMN - 1) ? 0.5f : 1.0f;
    const float sx = (x > 0 && x < DIMN - 1) ? 0.5f : 1.0f;

    float h[6];
    h[0] = sz * (GZ(Y, zp, y, x) - GZ(Y, zm, y, x));  // d2/dz2
    h[1] = sy * (GZ(Y, z, yp, x) - GZ(Y, z, ym, x));  // dz dy
    h[2] = sx * (GZ(Y, z, y, xp) - GZ(Y, z, y, xm));  // dz dx
    h[3] = sy * (GY(Y, z, yp, x) - GY(Y, z, ym, x));  // d2/dy2
    h[4] = sx * (GY(Y, z, y, xp) - GY(Y, z, y, xm));  // dy dx
    h[5] = sx * (GX(Y, z, y, xp) - GX(Y, z, y, xm));  // d2/dx2

    float o = b2[0];
#pragma unroll
    for (int oo = 0; oo < 10; ++oo) {
        float a = b1[oo];
#pragma unroll
        for (int f = 0; f < 6; ++f) a = fmaf(h[f], w1[oo * 6 + f], a);
        a = fmaxf(a, 0.f);
        o = fmaf(a, w2[oo], o);
    }
    out[idx] = 1.0f / (1.0f + __expf(-o));
}

// ---------------------------------------------------------------------------
extern "C" void kernel_launch(void* const* d_in, const int* in_sizes, int n_in,
                              void* d_out, int out_size, void* d_ws, size_t ws_size,
                              hipStream_t stream)
{
    const float* x  = (const float*)d_in[0];
    const float* cw = (const float*)d_in[1];
    const float* w1 = (const float*)d_in[2];
    const float* b1 = (const float*)d_in[3];
    const float* w2 = (const float*)d_in[4];
    const float* b2 = (const float*)d_in[5];
    float* outp = (float*)d_out;
    float* yws  = (float*)d_ws;   // 8,192,000 floats = 32.8 MB scratch

    dim3 blkA(32, 8, 1);
    dim3 grdA(DIMN / 8, DIMN, BATCH);
    conv3d_rep<<<grdA, blkA, 0, stream>>>(x, cw, yws);

    const int nblk = (int)(NPTS / 256);
    hess_mlp<<<nblk, 256, 0, stream>>>(yws, w1, b1, w2, b2, outp);
}